// Round 1
// baseline (75.665 us; speedup 1.0000x reference)
//
#include <hip/hip_runtime.h>

#define Bq   32
#define Cc   8
#define Oo   32
#define FSz  64
#define F2   4096
#define Pp   72
#define PIXT 8
#define NBLK 512            // F2 / PIXT
#define NTOT (Bq * F2)      // 131072 elements per channel
#define PATS 76             // padded LDS stride (bank-conflict-free, 16B aligned)

__global__ __launch_bounds__(256) void svconv_kernel(
    const float* __restrict__ x, const float* __restrict__ wgt,
    const float* __restrict__ bias, float* __restrict__ y,
    float* __restrict__ psum, float* __restrict__ psumsq)
{
    __shared__ float pat[PIXT][PATS];
    const int tid = threadIdx.x;
    const int o   = tid >> 3;      // 0..31
    const int pg  = tid & 7;       // pixel within tile
    const int fb  = blockIdx.x * PIXT;
    const int f   = fb + pg;
    const int h   = fb >> 6;       // tile is 8 consecutive pixels in one row
    const int w0  = fb & 63;

    // per-pixel weights: 72 floats in registers, read exactly once
    float4 wv[18];
    {
        const float* wp = wgt + (o * Pp) * F2 + f;
#pragma unroll
        for (int q = 0; q < 18; ++q) {
            wv[q].x = wp[(4 * q + 0) * F2];
            wv[q].y = wp[(4 * q + 1) * F2];
            wv[q].z = wp[(4 * q + 2) * F2];
            wv[q].w = wp[(4 * q + 3) * F2];
        }
    }
    const float bz = bias[o * F2 + f];

    float s = 0.f, ss = 0.f;

    for (int b = 0; b < Bq; ++b) {
        __syncthreads();   // previous iteration's reads done before overwrite
        // expand patches for this batch into LDS: pat[pix][p], p = c*9+kh*3+kw
#pragma unroll
        for (int e0 = 0; e0 < 3; ++e0) {
            int e = tid + e0 * 256;
            if (e < PIXT * Pp) {
                int pix = e / Pp;
                int p   = e - pix * Pp;
                int c   = p / 9;
                int r   = p - c * 9;
                int kh  = r / 3;
                int kw  = r - kh * 3;
                int gh  = h + kh - 1;
                int gw  = w0 + pix + kw - 1;
                float v = 0.f;
                if ((unsigned)gh < (unsigned)FSz && (unsigned)gw < (unsigned)FSz)
                    v = x[((b * Cc + c) * FSz + gh) * FSz + gw];
                pat[pix][p] = v;
            }
        }
        __syncthreads();

        const float4* pv = (const float4*)(&pat[pg][0]);
        float ax = 0.f, ay = 0.f, az = 0.f, aw = 0.f;
#pragma unroll
        for (int q = 0; q < 18; ++q) {
            float4 p4 = pv[q];
            ax = fmaf(wv[q].x, p4.x, ax);
            ay = fmaf(wv[q].y, p4.y, ay);
            az = fmaf(wv[q].z, p4.z, az);
            aw = fmaf(wv[q].w, p4.w, aw);
        }
        float acc = bz + ((ax + ay) + (az + aw));
        y[(b * Oo + o) * F2 + f] = acc;
        s += acc;
        ss = fmaf(acc, acc, ss);
    }

    // reduce sum/sumsq over the 8 pixel-lanes of each o (consecutive lanes)
    s  += __shfl_down(s, 4, 8);
    s  += __shfl_down(s, 2, 8);
    s  += __shfl_down(s, 1, 8);
    ss += __shfl_down(ss, 4, 8);
    ss += __shfl_down(ss, 2, 8);
    ss += __shfl_down(ss, 1, 8);
    if (pg == 0) {
        psum[o * NBLK + blockIdx.x]   = s;
        psumsq[o * NBLK + blockIdx.x] = ss;
    }
}

__global__ __launch_bounds__(256) void bnstats_kernel(
    const float* __restrict__ psum, const float* __restrict__ psumsq,
    const float* __restrict__ gamma, const float* __restrict__ beta,
    float* __restrict__ scsh)
{
    const int o = blockIdx.x;
    const int t = threadIdx.x;
    float s  = psum[o * NBLK + t]   + psum[o * NBLK + t + 256];
    float ss = psumsq[o * NBLK + t] + psumsq[o * NBLK + t + 256];
#pragma unroll
    for (int d = 32; d >= 1; d >>= 1) {
        s  += __shfl_down(s, d, 64);
        ss += __shfl_down(ss, d, 64);
    }
    __shared__ float ls[4], lss[4];
    int wv = t >> 6, ln = t & 63;
    if (ln == 0) { ls[wv] = s; lss[wv] = ss; }
    __syncthreads();
    if (t == 0) {
        float S   = (ls[0] + ls[1]) + (ls[2] + ls[3]);
        float SS  = (lss[0] + lss[1]) + (lss[2] + lss[3]);
        float mean = S / (float)NTOT;
        float var  = SS / (float)NTOT - mean * mean;
        float rstd = rsqrtf(var + 1e-5f);
        float scl  = gamma[o] * rstd;
        scsh[o]       = scl;
        scsh[Oo + o]  = beta[o] - mean * scl;
    }
}

__global__ __launch_bounds__(256) void bnapply_kernel(
    float* __restrict__ y, const float* __restrict__ scsh)
{
    int i = blockIdx.x * 256 + threadIdx.x;   // float4 index; total B*O*F2/4 = 1048576
    float4 v = ((const float4*)y)[i];
    int o = (i >> 10) & 31;                    // F2/4 = 1024 float4 per (b,o)
    float scl = scsh[o], sh = scsh[Oo + o];
    v.x = fmaf(v.x, scl, sh);
    v.y = fmaf(v.y, scl, sh);
    v.z = fmaf(v.z, scl, sh);
    v.w = fmaf(v.w, scl, sh);
    ((float4*)y)[i] = v;
}

extern "C" void kernel_launch(void* const* d_in, const int* in_sizes, int n_in,
                              void* d_out, int out_size, void* d_ws, size_t ws_size,
                              hipStream_t stream)
{
    const float* x     = (const float*)d_in[0];
    const float* wgt   = (const float*)d_in[1];
    const float* bias  = (const float*)d_in[2];
    const float* gamma = (const float*)d_in[3];
    const float* beta  = (const float*)d_in[4];
    float* y = (float*)d_out;

    float* psum   = (float*)d_ws;               // [Oo][NBLK]
    float* psumsq = psum + Oo * NBLK;           // [Oo][NBLK]
    float* scsh   = psumsq + Oo * NBLK;         // [2][Oo]

    svconv_kernel<<<NBLK, 256, 0, stream>>>(x, wgt, bias, y, psum, psumsq);
    bnstats_kernel<<<Oo, 256, 0, stream>>>(psum, psumsq, gamma, beta, scsh);
    bnapply_kernel<<<NTOT * Oo / 4 / 256, 256, 0, stream>>>(y, scsh);
}

// Round 2
// 55.256 us; speedup vs baseline: 1.3693x; 1.3693x over previous
//
#include <hip/hip_runtime.h>

#define Bq   32
#define Cc   8
#define Oo   32
#define FSz  64
#define F2   4096
#define Pp   72
#define TILE 16
#define NBLKS 256            // F2 / TILE
#define SLOTS 512            // NBLKS * 2 batch-halves
#define NTOT (Bq * F2)       // 131072 elements per channel

typedef _Float16 h2 __attribute__((ext_vector_type(2)));

#if __has_builtin(__builtin_amdgcn_fdot2)
#define DOT2(a, b, c) __builtin_amdgcn_fdot2((a), (b), (c), false)
#else
__device__ __forceinline__ float DOT2(h2 a, h2 b, float c) {
    return c + (float)a.x * (float)b.x + (float)a.y * (float)b.y;
}
#endif

__device__ __forceinline__ h2 bc_h2(unsigned u) { return __builtin_bit_cast(h2, u); }

// Block: 256 threads = (bg:2) x (og:8) x (f:16). Tile = 16 consecutive pixels in
// one row. Each thread computes 4 output channels (o = og*4+j) for its pixel,
// for 16 batches (its bg half). Weights: 4*72 f16 in 144 VGPRs, read once from
// HBM as full 64B granules. Patches: f16 in LDS, read as ds_read_b128, fed to
// v_dot2_f32_f16 (2 MACs/instr, f32 accum).
__global__ __launch_bounds__(256, 2) void svconv_kernel(
    const float* __restrict__ x, const float* __restrict__ wgt,
    const float* __restrict__ bias, float* __restrict__ y,
    float* __restrict__ psum, float* __restrict__ psumsq)
{
    __shared__ __align__(16) _Float16 patT[2 * TILE * Pp];   // 2 * 1152 halves
    const int tid  = threadIdx.x;
    const int f    = tid & 15;
    const int og   = (tid >> 4) & 7;
    const int bg   = tid >> 7;           // batch half
    const int t127 = tid & 127;
    const int fb   = blockIdx.x * TILE;
    const int col  = fb + f;
    const int h    = fb >> 6;            // row of this tile
    const int w0   = fb & 63;

    // ---- load per-pixel weights for 4 output channels, pack to f16 ----
    h2    w2[4][36];
    float bz[4];
#pragma unroll
    for (int j = 0; j < 4; ++j) {
        const int o = og * 4 + j;
        const float* wp = wgt + (size_t)(o * Pp) * F2 + col;
#pragma unroll
        for (int q = 0; q < 36; ++q) {
            float a = wp[(2 * q) * F2];
            float b = wp[(2 * q + 1) * F2];
            h2 t; t.x = (_Float16)a; t.y = (_Float16)b;
            w2[j][q] = t;
        }
        bz[j] = bias[o * F2 + col];
    }

    // ---- precompute the 9 patch-fill slots of this thread (batch-invariant) ----
    int xbase[9];
#pragma unroll
    for (int k = 0; k < 9; ++k) {
        int e   = t127 + k * 128;        // 0..1151, each of 1152 slots exactly once
        int pix = e / 72, p = e - pix * 72;
        int c   = p / 9,  r = p - c * 9;
        int kh  = r / 3,  kw = r - kh * 3;
        int gh  = h + kh - 1;
        int gw  = w0 + pix + kw - 1;
        xbase[k] = ((unsigned)gh < (unsigned)FSz && (unsigned)gw < (unsigned)FSz)
                       ? ((c * FSz + gh) * FSz + gw) : -1;
    }

    float s[4]  = {0.f, 0.f, 0.f, 0.f};
    float ss[4] = {0.f, 0.f, 0.f, 0.f};
    const int b0 = bg * 16;

    for (int bi = 0; bi < 16; ++bi) {
        const int b = b0 + bi;
        __syncthreads();                 // previous iteration's reads complete
        // fill this half's expanded patch tile (f16)
#pragma unroll
        for (int k = 0; k < 9; ++k) {
            float v = 0.f;
            if (xbase[k] >= 0) v = x[b * (Cc * FSz * FSz) + xbase[k]];
            patT[bg * (TILE * Pp) + t127 + k * 128] = (_Float16)v;
        }
        __syncthreads();

        const uint4* pv = (const uint4*)(patT + bg * (TILE * Pp) + f * Pp);
        uint4 u[9];
#pragma unroll
        for (int q = 0; q < 9; ++q) u[q] = pv[q];

#pragma unroll
        for (int j = 0; j < 4; ++j) {
            float acc = bz[j];
#pragma unroll
            for (int q = 0; q < 9; ++q) {
                acc = DOT2(w2[j][4 * q + 0], bc_h2(u[q].x), acc);
                acc = DOT2(w2[j][4 * q + 1], bc_h2(u[q].y), acc);
                acc = DOT2(w2[j][4 * q + 2], bc_h2(u[q].z), acc);
                acc = DOT2(w2[j][4 * q + 3], bc_h2(u[q].w), acc);
            }
            y[(b * Oo + og * 4 + j) * F2 + col] = acc;
            s[j] += acc;
            ss[j] = fmaf(acc, acc, ss[j]);
        }
    }

    // reduce over the 16 f-lanes (consecutive lanes within the wave)
#pragma unroll
    for (int j = 0; j < 4; ++j) {
#pragma unroll
        for (int d = 8; d >= 1; d >>= 1) {
            s[j]  += __shfl_down(s[j],  d, 16);
            ss[j] += __shfl_down(ss[j], d, 16);
        }
    }
    if (f == 0) {
        const int slot = blockIdx.x * 2 + bg;
#pragma unroll
        for (int j = 0; j < 4; ++j) {
            psum[(og * 4 + j) * SLOTS + slot]   = s[j];
            psumsq[(og * 4 + j) * SLOTS + slot] = ss[j];
        }
    }
}

__global__ __launch_bounds__(256) void bnstats_kernel(
    const float* __restrict__ psum, const float* __restrict__ psumsq,
    const float* __restrict__ gamma, const float* __restrict__ beta,
    float* __restrict__ scsh)
{
    const int o = blockIdx.x;
    const int t = threadIdx.x;
    float s  = psum[o * SLOTS + t]   + psum[o * SLOTS + t + 256];
    float ss = psumsq[o * SLOTS + t] + psumsq[o * SLOTS + t + 256];
#pragma unroll
    for (int d = 32; d >= 1; d >>= 1) {
        s  += __shfl_down(s, d, 64);
        ss += __shfl_down(ss, d, 64);
    }
    __shared__ float ls[4], lss[4];
    int wv = t >> 6, ln = t & 63;
    if (ln == 0) { ls[wv] = s; lss[wv] = ss; }
    __syncthreads();
    if (t == 0) {
        float S   = (ls[0] + ls[1]) + (ls[2] + ls[3]);
        float SS  = (lss[0] + lss[1]) + (lss[2] + lss[3]);
        float mean = S / (float)NTOT;
        float var  = SS / (float)NTOT - mean * mean;
        float rstd = rsqrtf(var + 1e-5f);
        float scl  = gamma[o] * rstd;
        scsh[o]      = scl;
        scsh[Oo + o] = beta[o] - mean * scl;
    }
}

__global__ __launch_bounds__(256) void bnapply_kernel(
    float* __restrict__ y, const float* __restrict__ scsh)
{
    int i = blockIdx.x * 256 + threadIdx.x;    // float4 index
    float4 v = ((const float4*)y)[i];
    int o = (i >> 10) & 31;                    // F2/4 = 1024 float4 per (b,o)
    float scl = scsh[o], sh = scsh[Oo + o];
    v.x = fmaf(v.x, scl, sh);
    v.y = fmaf(v.y, scl, sh);
    v.z = fmaf(v.z, scl, sh);
    v.w = fmaf(v.w, scl, sh);
    ((float4*)y)[i] = v;
}

extern "C" void kernel_launch(void* const* d_in, const int* in_sizes, int n_in,
                              void* d_out, int out_size, void* d_ws, size_t ws_size,
                              hipStream_t stream)
{
    const float* x     = (const float*)d_in[0];
    const float* wgt   = (const float*)d_in[1];
    const float* bias  = (const float*)d_in[2];
    const float* gamma = (const float*)d_in[3];
    const float* beta  = (const float*)d_in[4];
    float* y = (float*)d_out;

    float* psum   = (float*)d_ws;               // [Oo][SLOTS]
    float* psumsq = psum + Oo * SLOTS;          // [Oo][SLOTS]
    float* scsh   = psumsq + Oo * SLOTS;        // [2][Oo]

    svconv_kernel<<<NBLKS, 256, 0, stream>>>(x, wgt, bias, y, psum, psumsq);
    bnstats_kernel<<<Oo, 256, 0, stream>>>(psum, psumsq, gamma, beta, scsh);
    bnapply_kernel<<<NTOT * Oo / 4 / 256, 256, 0, stream>>>(y, scsh);
}